// Round 14
// baseline (166.780 us; speedup 1.0000x reference)
//
#include <hip/hip_runtime.h>
#include <hip/hip_cooperative_groups.h>
#include <math.h>

namespace cg = cooperative_groups;

#define NB   4
#define SL   1024
#define NTOK (NB*SL)      // 4096
#define DM   64
#define DI   128
#define DSt  128
#define SEGLEN 8
#define NSEG (SL/SEGLEN)  // 128
#define NSEG_ALL (NB*NSEG) // 512

// ---- workspace layout (float offsets) ----
#define OFF_GATE   0
#define OFF_DELTA  (OFF_GATE  + NTOK*DI)
#define OFF_BM     (OFF_DELTA + NTOK*DI)
#define OFF_CM     (OFF_BM    + NTOK*DSt)
#define OFF_XPOOL  (OFF_CM    + NTOK*DSt)
#define OFF_ABAR   (OFF_XPOOL + NTOK)          // used only by fallback path
#define OFF_HEND   (OFF_ABAR  + NTOK*DSt)
#define OFF_P      (OFF_HEND  + NSEG_ALL*DSt)
#define OFF_W4     (OFF_P     + NSEG_ALL*DSt)  // 2048 float4

#define PROJ_TOK 16
#define PROJ_TG  (NTOK/PROJ_TOK)   // 256 token groups

static __device__ __forceinline__ float wave64_sum(float v) {
#pragma unroll
    for (int m = 32; m >= 1; m >>= 1) v += __shfl_xor(v, m, 64);
    return v;
}

static __device__ __forceinline__ float fast_exp2(float x) {
    float r;
    asm("v_exp_f32 %0, %1" : "=v"(r) : "v"(x));
    return r;
}

static __device__ __forceinline__ float softplus_f(float x) {
    return fmaxf(x, 0.f) + __logf(1.f + __expf(-fabsf(x)));
}

static __device__ __forceinline__ void pin4(float4& v) {
    asm volatile("" : "+v"(v.x), "+v"(v.y), "+v"(v.z), "+v"(v.w));
}

// =====================================================================
// FUSED cooperative kernel: 512 blocks x 256 threads, 2 blocks/CU.
// P1 proj (2 units/block) -> grid.sync -> P2 abar+scan1 (own segment,
// Abar kept in persistent LDS) -> grid.sync -> P3 tail (own segment).
// =====================================================================
__global__ __launch_bounds__(256, 2) void k_fused(
    const float* __restrict__ x, const float* __restrict__ W_in,
    const float* __restrict__ W_delta, const float* __restrict__ b_delta,
    const float* __restrict__ W_B, const float* __restrict__ b_B,
    const float* __restrict__ W_C, const float* __restrict__ b_C,
    const float* __restrict__ A, const float* __restrict__ W_out,
    const float* __restrict__ ln_w, const float* __restrict__ ln_b,
    float* __restrict__ ws, float* __restrict__ out)
{
    __shared__ __align__(16) unsigned char smem[40960];
    // phase1: Wl f4[2048] @0 (32KB), xl f[1024] @32768 (4KB)
    // phase2: psum f[4][8][64] @0 (8KB)
    // phase3: prod f[8][132] @0, vbuf f[4][128] @8192, yb f[8] @10240
    // persistent: abC f[8][128] @36864 (4KB)
    float4* Wl   = (float4*)smem;
    float*  xl   = (float*)(smem + 32768);
    float*  psum = (float*)smem;                    // [igrp][t][lane]
    float*  prod = (float*)smem;                    // [t][132]
    float*  vbuf = (float*)(smem + 8192);           // [wv][128]
    float*  yb   = (float*)(smem + 10240);          // [8]
    float*  abC  = (float*)(smem + 36864);          // [t][128]

    const int tid = threadIdx.x;
    cg::grid_group grid = cg::this_grid();

    // ---- W4 repack (blocks 0..7) ----
    if (blockIdx.x < 8) {
        const int f = blockIdx.x*256 + tid;
        const int dd = f >> 5, q = f & 31;
        ((float4*)(ws + OFF_W4))[q*64 + dd] = ((const float4*)W_out)[f];
    }

    // ================= P1: projections, 2 units per block =================
#pragma unroll 1
    for (int u = 0; u < 2; ++u) {
        const int unit = blockIdx.x*2 + u;
        const int cat  = unit >> 8;
        const int tg   = unit & 255;
        const int tok0 = tg * PROJ_TOK;
        const int l    = tid & 63;
        const int w    = tid >> 6;

        const float* Wbase; const float* bias; float* dst;
        if      (cat == 0) { Wbase = W_in + DI*DM; bias = nullptr; dst = ws + OFF_GATE;  }
        else if (cat == 1) { Wbase = W_delta;      bias = b_delta; dst = ws + OFF_DELTA; }
        else if (cat == 2) { Wbase = W_B;          bias = b_B;     dst = ws + OFF_BM;    }
        else               { Wbase = W_C;          bias = b_C;     dst = ws + OFF_CM;    }

        __syncthreads();   // LDS reuse guard between units
        {   // stage x tile (256 f4) + weight panel (2048 f4), coalesced
            const float4* xg = (const float4*)(x + tok0*DM);
            ((float4*)xl)[tid] = xg[tid];
            const float4* Wg = (const float4*)Wbase;
#pragma unroll
            for (int j = 0; j < 8; ++j) {
                const int f = tid + j*256;
                const int row = f >> 4, k = f & 15;
                Wl[row*16 + (k ^ (row & 15))] = Wg[f];
            }
        }
        __syncthreads();

        float4 w0[16], w1[16];
#pragma unroll
        for (int k = 0; k < 16; ++k) {
            w0[k] = Wl[l*16      + (k ^ (l & 15))];
            w1[k] = Wl[(l+64)*16 + (k ^ (l & 15))];
        }
#pragma unroll
        for (int k = 0; k < 16; ++k) { pin4(w0[k]); pin4(w1[k]); }

        float bias0 = 0.f, bias1 = 0.f;
        if (bias) { bias0 = bias[l]; bias1 = bias[l+64]; }

#pragma unroll
        for (int it = 0; it < PROJ_TOK/4; ++it) {
            const int tl = it*4 + w;
            float a0=0.f,a1=0.f,a2=0.f,a3=0.f, c0=0.f,c1=0.f,c2=0.f,c3=0.f;
#pragma unroll
            for (int k = 0; k < 16; ++k) {
                const float4 xv = *(const float4*)(xl + tl*DM + 4*k);  // bcast
                a0 = fmaf(w0[k].x, xv.x, a0);
                a1 = fmaf(w0[k].y, xv.y, a1);
                a2 = fmaf(w0[k].z, xv.z, a2);
                a3 = fmaf(w0[k].w, xv.w, a3);
                c0 = fmaf(w1[k].x, xv.x, c0);
                c1 = fmaf(w1[k].y, xv.y, c1);
                c2 = fmaf(w1[k].z, xv.z, c2);
                c3 = fmaf(w1[k].w, xv.w, c3);
            }
            float ra = (a0+a1) + (a2+a3) + bias0;
            float rb = (c0+c1) + (c2+c3) + bias1;
            if (cat == 1) { ra = softplus_f(ra); rb = softplus_f(rb); }
            const int tok = tok0 + tl;
            dst[tok*128 + l]      = ra;   // coalesced
            dst[tok*128 + 64 + l] = rb;
        }

        if (cat == 0) {   // x_pool
            float wp = 0.f;
#pragma unroll 8
            for (int i = 0; i < DI; ++i) wp += W_in[i*DM + l];
            wp *= (1.0f/DI);
#pragma unroll
            for (int it = 0; it < PROJ_TOK/4; ++it) {
                const int tl = it*4 + w;
                float v = xl[tl*DM + l] * wp;
                v = wave64_sum(v);
                if (l == 0) ws[OFF_XPOOL + tok0 + tl] = v;
            }
        }
    }

    grid.sync();   // all gate/delta/Bm/Cm/xpool visible

    // ========== P2: abar + scan1, own segment (both s-halves) ==========
    {
        const int g  = blockIdx.x;            // segment
        const int t0 = g * SEGLEN;
        const int lane = tid & 63;
        const int igrp = tid >> 6;
        const float* delta = ws + OFF_DELTA;

#pragma unroll 1
        for (int u = 0; u < 2; ++u) {
            const int sh = u;
            const int s  = sh*64 + lane;

            float areg[32];
#pragma unroll
            for (int i = 0; i < 32; ++i)
                areg[i] = A[(igrp*32 + i)*DSt + s] * 1.44269504f;

            __syncthreads();   // psum reuse guard
#pragma unroll
            for (int t = 0; t < SEGLEN; ++t) {
                const float* dv = delta + (t0 + t)*DI + igrp*32;
                float a0=0.f,a1=0.f,a2=0.f,a3=0.f;
#pragma unroll
                for (int q = 0; q < 8; ++q) {
                    const float4 d4 = *(const float4*)(dv + 4*q);  // bcast
                    a0 += fast_exp2(d4.x * areg[4*q    ]);
                    a1 += fast_exp2(d4.y * areg[4*q + 1]);
                    a2 += fast_exp2(d4.z * areg[4*q + 2]);
                    a3 += fast_exp2(d4.w * areg[4*q + 3]);
                }
                psum[(igrp*SEGLEN + t)*64 + lane] = (a0+a1) + (a2+a3);
            }
            __syncthreads();

#pragma unroll
            for (int it = tid; it < SEGLEN*64; it += 256) {
                const int t = it >> 6, l2 = it & 63;
                float v = (psum[(0*SEGLEN + t)*64 + l2] + psum[(1*SEGLEN + t)*64 + l2])
                        + (psum[(2*SEGLEN + t)*64 + l2] + psum[(3*SEGLEN + t)*64 + l2]);
                abC[t*DSt + sh*64 + l2] = v * (1.0f/DI);   // persistent LDS
            }
            __syncthreads();

            if (tid < 64) {   // 8-step local scan for this s-half
                const float* Bm    = ws + OFF_BM;
                const float* xpool = ws + OFF_XPOOL;
                float bx[SEGLEN];
#pragma unroll
                for (int t = 0; t < SEGLEN; ++t)
                    bx[t] = Bm[(t0 + t)*DSt + s] * xpool[t0 + t];
                float h = 0.f, pr = 1.f;
#pragma unroll
                for (int t = 0; t < SEGLEN; ++t) {
                    const float a = abC[t*DSt + s];
                    h = fmaf(a, h, bx[t]);
                    pr *= a;
                }
                ws[OFF_HEND + g*DSt + s] = h;
                ws[OFF_P    + g*DSt + s] = pr;
            }
        }
    }

    grid.sync();   // all HEND/P visible

    // ================= P3: tail, own segment =================
    {
        const int b   = blockIdx.x >> 7;
        const int seg = blockIdx.x & 127;
        const int t0  = b*SL + seg*SEGLEN;

        __syncthreads();   // prod overlaps psum region
        if (tid < 128) {
            const int s = tid;
            const float* Bm    = ws + OFF_BM;
            const float* Cm    = ws + OFF_CM;
            const float* xpool = ws + OFF_XPOOL;
            const float* hend  = ws + OFF_HEND;
            const float* P     = ws + OFF_P;

            float aA[SEGLEN], aB[SEGLEN], aC[SEGLEN];
#pragma unroll
            for (int t = 0; t < SEGLEN; ++t) {
                aA[t] = abC[t*DSt + s];                     // own segment, LDS
                aB[t] = Bm[(t0 + t)*DSt + s] * xpool[t0 + t];
                aC[t] = Cm[(t0 + t)*DSt + s];
            }
            float h = 0.f;
#pragma unroll 8
            for (int j = 0; j < seg; ++j) {
                const int idx = (b*NSEG + j)*DSt + s;
                h = fmaf(P[idx], h, hend[idx]);
            }
#pragma unroll
            for (int t = 0; t < SEGLEN; ++t) {
                h = fmaf(aA[t], h, aB[t]);
                prod[t*132 + s] = aC[t] * h;
            }
        }
        __syncthreads();

        if (tid < 128) {   // y reduce: 16 lanes per token
            const int t = tid >> 4, r = tid & 15;
            float4 u0 = *(const float4*)(&prod[t*132 + r*8]);
            float4 u1 = *(const float4*)(&prod[t*132 + r*8 + 4]);
            float acc = ((u0.x+u0.y) + (u0.z+u0.w)) + ((u1.x+u1.y) + (u1.z+u1.w));
#pragma unroll
            for (int m = 1; m <= 8; m <<= 1) acc += __shfl_xor(acc, m, 64);
            if (r == 0) yb[t] = acc;
        }
        __syncthreads();

        // phase B: 4 waves x 2 tokens; vbuf wave-private -> no barriers
        const float* gate = ws + OFF_GATE;
        const float4* W4  = (const float4*)(ws + OFF_W4);
        const int d  = tid & 63;
        const int wv = tid >> 6;
        const float lw = ln_w[d], lb = ln_b[d];
#pragma unroll
        for (int jt = 0; jt < 2; ++jt) {
            const int tl  = wv*2 + jt;
            const int tok = t0 + tl;
            const float yt = yb[tl];
            const float g0 = gate[tok*DI + d];
            const float g1 = gate[tok*DI + 64 + d];
            vbuf[wv*DI + d]      = yt * (g0 / (1.f + __expf(-g0)));
            vbuf[wv*DI + 64 + d] = yt * (g1 / (1.f + __expf(-g1)));

            float ac0 = 0.f, ac1 = 0.f, ac2 = 0.f, ac3 = 0.f;
#pragma unroll 8
            for (int q = 0; q < 32; ++q) {
                const float4 wv4 = W4[q*64 + d];                       // coalesced
                const float4 vv  = *(const float4*)(&vbuf[wv*DI + q*4]); // bcast
                ac0 = fmaf(wv4.x, vv.x, ac0);
                ac1 = fmaf(wv4.y, vv.y, ac1);
                ac2 = fmaf(wv4.z, vv.z, ac2);
                ac3 = fmaf(wv4.w, vv.w, ac3);
            }
            const float z  = (ac0+ac1) + (ac2+ac3) + x[tok*DM + d];
            const float s1 = wave64_sum(z);
            const float s2 = wave64_sum(z*z);
            const float mu  = s1 * (1.f/64.f);
            const float var = s2 * (1.f/64.f) - mu*mu;
            out[tok*DM + d] = (z - mu) * rsqrtf(var + 1e-5f) * lw + lb;
        }
    }
}

// =====================================================================
// Fallback path: R13's three kernels (used only if coop launch fails)
// =====================================================================
__global__ __launch_bounds__(256, 2) void k_proj(
    const float* __restrict__ x, const float* __restrict__ W_in,
    const float* __restrict__ W_delta, const float* __restrict__ b_delta,
    const float* __restrict__ W_B, const float* __restrict__ b_B,
    const float* __restrict__ W_C, const float* __restrict__ b_C,
    const float* __restrict__ W_out, float* __restrict__ ws)
{
    __shared__ float  xl[PROJ_TOK*DM];
    __shared__ float4 Wl[DI*16];
    const int tid = threadIdx.x;

    if (blockIdx.x == 4*PROJ_TG) {
        const float4* Wg = (const float4*)W_out;
        float4* W4 = (float4*)(ws + OFF_W4);
#pragma unroll
        for (int j = 0; j < 8; ++j) {
            const int f = tid + j*256;
            const int d = f >> 5, q = f & 31;
            W4[q*64 + d] = Wg[f];
        }
        return;
    }

    const int l   = tid & 63;
    const int w   = tid >> 6;
    const int cat = blockIdx.x >> 8;
    const int tg  = blockIdx.x & 255;
    const int tok0 = tg * PROJ_TOK;

    const float* Wbase; const float* bias; float* dst;
    if      (cat == 0) { Wbase = W_in + DI*DM; bias = nullptr; dst = ws + OFF_GATE;  }
    else if (cat == 1) { Wbase = W_delta;      bias = b_delta; dst = ws + OFF_DELTA; }
    else if (cat == 2) { Wbase = W_B;          bias = b_B;     dst = ws + OFF_BM;    }
    else               { Wbase = W_C;          bias = b_C;     dst = ws + OFF_CM;    }

    {
        const float4* xg = (const float4*)(x + tok0*DM);
        ((float4*)xl)[tid] = xg[tid];
        const float4* Wg = (const float4*)Wbase;
#pragma unroll
        for (int j = 0; j < 8; ++j) {
            const int f = tid + j*256;
            const int row = f >> 4, k = f & 15;
            Wl[row*16 + (k ^ (row & 15))] = Wg[f];
        }
    }
    __syncthreads();

    float4 w0[16], w1[16];
#pragma unroll
    for (int k = 0; k < 16; ++k) {
        w0[k] = Wl[l*16      + (k ^ (l & 15))];
        w1[k] = Wl[(l+64)*16 + (k ^ (l & 15))];
    }
#pragma unroll
    for (int k = 0; k < 16; ++k) { pin4(w0[k]); pin4(w1[k]); }

    float bias0 = 0.f, bias1 = 0.f;
    if (bias) { bias0 = bias[l]; bias1 = bias[l+64]; }

#pragma unroll
    for (int it = 0; it < PROJ_TOK/4; ++it) {
        const int tl = it*4 + w;
        float a0=0.f,a1=0.f,a2=0.f,a3=0.f, c0=0.f,c1=0.f,c2=0.f,c3=0.f;
#pragma unroll
        for (int k = 0; k < 16; ++k) {
            const float4 xv = *(const float4*)(xl + tl*DM + 4*k);
            a0 = fmaf(w0[k].x, xv.x, a0);
            a1 = fmaf(w0[k].y, xv.y, a1);
            a2 = fmaf(w0[k].z, xv.z, a2);
            a3 = fmaf(w0[k].w, xv.w, a3);
            c0 = fmaf(w1[k].x, xv.x, c0);
            c1 = fmaf(w1[k].y, xv.y, c1);
            c2 = fmaf(w1[k].z, xv.z, c2);
            c3 = fmaf(w1[k].w, xv.w, c3);
        }
        float ra = (a0+a1) + (a2+a3) + bias0;
        float rb = (c0+c1) + (c2+c3) + bias1;
        if (cat == 1) { ra = softplus_f(ra); rb = softplus_f(rb); }
        const int tok = tok0 + tl;
        dst[tok*128 + l]      = ra;
        dst[tok*128 + 64 + l] = rb;
    }

    if (cat == 0) {
        float wp = 0.f;
#pragma unroll 8
        for (int i = 0; i < DI; ++i) wp += W_in[i*DM + l];
        wp *= (1.0f/DI);
#pragma unroll
        for (int it = 0; it < PROJ_TOK/4; ++it) {
            const int tl = it*4 + w;
            float v = xl[tl*DM + l] * wp;
            v = wave64_sum(v);
            if (l == 0) ws[OFF_XPOOL + tok0 + tl] = v;
        }
    }
}

__global__ __launch_bounds__(256) void k_abar_scan1(const float* __restrict__ A,
                                                    float* __restrict__ ws)
{
    __shared__ float psum[4][SEGLEN][64];
    __shared__ float abL[SEGLEN][64];
    const int tid  = threadIdx.x;
    const int lane = tid & 63;
    const int igrp = tid >> 6;
    const int g    = blockIdx.x >> 1;
    const int sh   = blockIdx.x & 1;
    const int s    = sh*64 + lane;
    const int t0   = g * SEGLEN;

    float areg[32];
#pragma unroll
    for (int i = 0; i < 32; ++i)
        areg[i] = A[(igrp*32 + i)*DSt + s] * 1.44269504f;

    const float* delta = ws + OFF_DELTA;
    float*       Abar  = ws + OFF_ABAR;

#pragma unroll
    for (int t = 0; t < SEGLEN; ++t) {
        const float* dv = delta + (t0 + t)*DI + igrp*32;
        float a0=0.f,a1=0.f,a2=0.f,a3=0.f;
#pragma unroll
        for (int q = 0; q < 8; ++q) {
            const float4 d4 = *(const float4*)(dv + 4*q);
            a0 += fast_exp2(d4.x * areg[4*q    ]);
            a1 += fast_exp2(d4.y * areg[4*q + 1]);
            a2 += fast_exp2(d4.z * areg[4*q + 2]);
            a3 += fast_exp2(d4.w * areg[4*q + 3]);
        }
        psum[igrp][t][lane] = (a0+a1) + (a2+a3);
    }
    __syncthreads();

#pragma unroll
    for (int it = tid; it < SEGLEN*64; it += 256) {
        const int t = it >> 6, l2 = it & 63;
        float v = (psum[0][t][l2] + psum[1][t][l2])
                + (psum[2][t][l2] + psum[3][t][l2]);
        v *= (1.0f/DI);
        abL[t][l2] = v;
        Abar[(t0 + t)*DSt + sh*64 + l2] = v;
    }
    __syncthreads();

    if (tid < 64) {
        const float* Bm    = ws + OFF_BM;
        const float* xpool = ws + OFF_XPOOL;
        float bx[SEGLEN];
#pragma unroll
        for (int t = 0; t < SEGLEN; ++t)
            bx[t] = Bm[(t0 + t)*DSt + s] * xpool[t0 + t];
        float h = 0.f, pr = 1.f;
#pragma unroll
        for (int t = 0; t < SEGLEN; ++t) {
            const float a = abL[t][lane];
            h = fmaf(a, h, bx[t]);
            pr *= a;
        }
        ws[OFF_HEND + g*DSt + s] = h;
        ws[OFF_P    + g*DSt + s] = pr;
    }
}

__global__ __launch_bounds__(128) void k_tail(
    const float* __restrict__ x, const float* __restrict__ ln_w,
    const float* __restrict__ ln_b, const float* __restrict__ ws,
    float* __restrict__ out)
{
    __shared__ float prod[SEGLEN][132];
    __shared__ float y_lds[SEGLEN];
    __shared__ float vbuf[2][DI];

    const int tid = threadIdx.x;
    const int s   = tid;
    const int b   = blockIdx.x >> 7;
    const int seg = blockIdx.x & 127;
    const int t0  = b*SL + seg*SEGLEN;

    const float* Abar  = ws + OFF_ABAR;
    const float* Bm    = ws + OFF_BM;
    const float* Cm    = ws + OFF_CM;
    const float* xpool = ws + OFF_XPOOL;
    const float* hend  = ws + OFF_HEND;
    const float* P     = ws + OFF_P;

    float aA[SEGLEN], aB[SEGLEN], aC[SEGLEN];
#pragma unroll
    for (int t = 0; t < SEGLEN; ++t) {
        aA[t] = Abar[(t0 + t)*DSt + s];
        aB[t] = Bm[(t0 + t)*DSt + s] * xpool[t0 + t];
        aC[t] = Cm[(t0 + t)*DSt + s];
    }
    float h = 0.f;
#pragma unroll 8
    for (int j = 0; j < seg; ++j) {
        const int idx = (b*NSEG + j)*DSt + s;
        h = fmaf(P[idx], h, hend[idx]);
    }
#pragma unroll
    for (int t = 0; t < SEGLEN; ++t) {
        h = fmaf(aA[t], h, aB[t]);
        prod[t][s] = aC[t] * h;
    }
    __syncthreads();

    {
        const int t = s >> 4, r = s & 15;
        float4 u0 = *(const float4*)(&prod[t][r*8]);
        float4 u1 = *(const float4*)(&prod[t][r*8 + 4]);
        float acc = ((u0.x+u0.y) + (u0.z+u0.w)) + ((u1.x+u1.y) + (u1.z+u1.w));
#pragma unroll
        for (int m = 1; m <= 8; m <<= 1) acc += __shfl_xor(acc, m, 64);
        if (r == 0) y_lds[t] = acc;
    }
    __syncthreads();

    const float* gate = ws + OFF_GATE;
    const float4* W4  = (const float4*)(ws + OFF_W4);
    const int d  = tid & 63;
    const int wv = tid >> 6;
    const float lw = ln_w[d], lb = ln_b[d];
#pragma unroll 2
    for (int jt = 0; jt < 4; ++jt) {
        const int tl  = wv*4 + jt;
        const int tok = t0 + tl;
        const float yt = y_lds[tl];
        const float g0 = gate[tok*DI + d];
        const float g1 = gate[tok*DI + 64 + d];
        vbuf[wv][d]      = yt * (g0 / (1.f + __expf(-g0)));
        vbuf[wv][64 + d] = yt * (g1 / (1.f + __expf(-g1)));

        float ac0 = 0.f, ac1 = 0.f, ac2 = 0.f, ac3 = 0.f;
#pragma unroll 8
        for (int q = 0; q < 32; ++q) {
            const float4 wv4 = W4[q*64 + d];
            const float4 vv  = *(const float4*)(&vbuf[wv][q*4]);
            ac0 = fmaf(wv4.x, vv.x, ac0);
            ac1 = fmaf(wv4.y, vv.y, ac1);
            ac2 = fmaf(wv4.z, vv.z, ac2);
            ac3 = fmaf(wv4.w, vv.w, ac3);
        }
        const float z  = (ac0+ac1) + (ac2+ac3) + x[tok*DM + d];
        const float s1 = wave64_sum(z);
        const float s2 = wave64_sum(z*z);
        const float mu  = s1 * (1.f/64.f);
        const float var = s2 * (1.f/64.f) - mu*mu;
        out[tok*DM + d] = (z - mu) * rsqrtf(var + 1e-5f) * lw + lb;
    }
}

extern "C" void kernel_launch(void* const* d_in, const int* in_sizes, int n_in,
                              void* d_out, int out_size, void* d_ws, size_t ws_size,
                              hipStream_t stream) {
    const float* x       = (const float*)d_in[0];
    const float* W_in    = (const float*)d_in[1];
    const float* W_delta = (const float*)d_in[2];
    const float* b_delta = (const float*)d_in[3];
    const float* W_B     = (const float*)d_in[4];
    const float* b_B     = (const float*)d_in[5];
    const float* W_C     = (const float*)d_in[6];
    const float* b_C     = (const float*)d_in[7];
    const float* A       = (const float*)d_in[8];
    const float* W_out   = (const float*)d_in[9];
    const float* ln_w    = (const float*)d_in[10];
    const float* ln_b    = (const float*)d_in[11];
    float* out = (float*)d_out;
    float* ws  = (float*)d_ws;

    void* args[] = {
        (void*)&x, (void*)&W_in, (void*)&W_delta, (void*)&b_delta,
        (void*)&W_B, (void*)&b_B, (void*)&W_C, (void*)&b_C,
        (void*)&A, (void*)&W_out, (void*)&ln_w, (void*)&ln_b,
        (void*)&ws, (void*)&out
    };
    hipError_t err = hipLaunchCooperativeKernel((const void*)k_fused,
                                                dim3(NSEG_ALL), dim3(256),
                                                args, 0, stream);
    if (err != hipSuccess) {   // deterministic fallback: R13 3-kernel path
        hipLaunchKernelGGL(k_proj, dim3(4*PROJ_TG + 1), dim3(256), 0, stream,
                           x, W_in, W_delta, b_delta, W_B, b_B, W_C, b_C, W_out, ws);
        hipLaunchKernelGGL(k_abar_scan1, dim3(2*NSEG_ALL), dim3(256), 0, stream, A, ws);
        hipLaunchKernelGGL(k_tail,       dim3(NSEG_ALL),   dim3(128), 0, stream,
                           x, ln_w, ln_b, ws, out);
    }
}

// Round 15
// 49.589 us; speedup vs baseline: 3.3633x; 3.3633x over previous
//
#include <hip/hip_runtime.h>
#include <math.h>

#define NB   4
#define SL   1024
#define NTOK (NB*SL)      // 4096
#define DM   64
#define DI   128
#define DSt  128
#define SEGLEN 8
#define NSEG (SL/SEGLEN)  // 128
#define NSEG_ALL (NB*NSEG) // 512

// ---- workspace layout (float offsets) ----
#define OFF_GATE   0
#define OFF_DELTA  (OFF_GATE  + NTOK*DI)
#define OFF_BM     (OFF_DELTA + NTOK*DI)
#define OFF_CM     (OFF_BM    + NTOK*DSt)
#define OFF_XPOOL  (OFF_CM    + NTOK*DSt)
#define OFF_ABAR   (OFF_XPOOL + NTOK)
#define OFF_HEND   (OFF_ABAR  + NTOK*DSt)
#define OFF_P      (OFF_HEND  + NSEG_ALL*DSt)
#define OFF_Y      (OFF_P     + NSEG_ALL*DSt)
#define OFF_W4     (OFF_Y     + NTOK)        // 2048 float4

#define PROJ_TOK 16
#define PROJ_TG  (NTOK/PROJ_TOK)   // 256 token groups

static __device__ __forceinline__ float wave64_sum(float v) {
#pragma unroll
    for (int m = 32; m >= 1; m >>= 1) v += __shfl_xor(v, m, 64);
    return v;
}

static __device__ __forceinline__ float fast_exp2(float x) {
    float r;
    asm("v_exp_f32 %0, %1" : "=v"(r) : "v"(x));
    return r;
}

static __device__ __forceinline__ float softplus_f(float x) {
    return fmaxf(x, 0.f) + __logf(1.f + __expf(-fabsf(x)));
}

static __device__ __forceinline__ void pin4(float4& v) {
    asm volatile("" : "+v"(v.x), "+v"(v.y), "+v"(v.z), "+v"(v.w));
}

// async global->LDS 16B: linear LDS dest (wave base + lane*16), per-lane src
#if __has_builtin(__builtin_amdgcn_global_load_lds)
#define HAVE_GLL 1
static __device__ __forceinline__ void gload_lds16(const float4* g, float4* l) {
    __builtin_amdgcn_global_load_lds(
        (const __attribute__((address_space(1))) void*)g,
        (__attribute__((address_space(3))) void*)l,
        16, 0, 0);
}
#else
#define HAVE_GLL 0
#endif

// ---- K1: projections. grid = 4 cats x 256 token-groups (+1 repack block).
// Staging via global_load_lds(16): LDS linear, swizzle moved to the global
// SOURCE address (involution) so per-lane row reads stay conflict-free.
__global__ __launch_bounds__(256, 2) void k_proj(
    const float* __restrict__ x, const float* __restrict__ W_in,
    const float* __restrict__ W_delta, const float* __restrict__ b_delta,
    const float* __restrict__ W_B, const float* __restrict__ b_B,
    const float* __restrict__ W_C, const float* __restrict__ b_C,
    const float* __restrict__ W_out, float* __restrict__ ws)
{
    __shared__ float  xl[PROJ_TOK*DM];   // 4 KB
    __shared__ float4 Wl[DI*16];         // 32 KB, holds Wg[row][k^(row&15)] at [row][k]
    const int tid = threadIdx.x;

    if (blockIdx.x == 4*PROJ_TG) {       // tail: W_out repack W4[q*64+d]
        const float4* Wg = (const float4*)W_out;
        float4* W4 = (float4*)(ws + OFF_W4);
#pragma unroll
        for (int j = 0; j < 8; ++j) {
            const int f = tid + j*256;
            const int d = f >> 5, q = f & 31;
            W4[q*64 + d] = Wg[f];
        }
        return;
    }

    const int l   = tid & 63;
    const int w   = tid >> 6;
    const int cat = blockIdx.x >> 8;     // 0 gate, 1 delta, 2 B, 3 C
    const int tg  = blockIdx.x & 255;
    const int tok0 = tg * PROJ_TOK;

    const float* Wbase; const float* bias; float* dst;
    if      (cat == 0) { Wbase = W_in + DI*DM; bias = nullptr; dst = ws + OFF_GATE;  }
    else if (cat == 1) { Wbase = W_delta;      bias = b_delta; dst = ws + OFF_DELTA; }
    else if (cat == 2) { Wbase = W_B;          bias = b_B;     dst = ws + OFF_BM;    }
    else               { Wbase = W_C;          bias = b_C;     dst = ws + OFF_CM;    }

    {   // stage x tile (256 f4, linear) + weight panel (2048 f4, src-swizzled)
        const float4* xg = (const float4*)(x + tok0*DM);
        const float4* Wg = (const float4*)Wbase;
#if HAVE_GLL
        gload_lds16(xg + tid, ((float4*)xl) + tid);
#pragma unroll
        for (int j = 0; j < 8; ++j) {
            const int f   = tid + j*256;         // linear LDS f4 index
            const int row = f >> 4, kk = f & 15;
            const int src = row*16 + (kk ^ (row & 15));   // involution
            gload_lds16(Wg + src, Wl + f);
        }
#else
        ((float4*)xl)[tid] = xg[tid];
#pragma unroll
        for (int j = 0; j < 8; ++j) {
            const int f = tid + j*256;
            const int row = f >> 4, k = f & 15;
            Wl[row*16 + (k ^ (row & 15))] = Wg[f];
        }
#endif
    }
    __syncthreads();   // drains vmcnt before ds_read (compiler-enforced)

    // two weight rows per lane -> 128 pinned VGPRs; swizzled (2-way max) reads
    float4 w0[16], w1[16];
#pragma unroll
    for (int k = 0; k < 16; ++k) {
        w0[k] = Wl[l*16      + (k ^ (l & 15))];
        w1[k] = Wl[(l+64)*16 + (k ^ (l & 15))];
    }
#pragma unroll
    for (int k = 0; k < 16; ++k) { pin4(w0[k]); pin4(w1[k]); }

    float bias0 = 0.f, bias1 = 0.f;
    if (bias) { bias0 = bias[l]; bias1 = bias[l+64]; }

#pragma unroll
    for (int it = 0; it < PROJ_TOK/4; ++it) {
        const int tl = it*4 + w;        // wave-uniform local token
        float a0=0.f,a1=0.f,a2=0.f,a3=0.f, c0=0.f,c1=0.f,c2=0.f,c3=0.f;
#pragma unroll
        for (int k = 0; k < 16; ++k) {
            const float4 xv = *(const float4*)(xl + tl*DM + 4*k);  // broadcast
            a0 = fmaf(w0[k].x, xv.x, a0);
            a1 = fmaf(w0[k].y, xv.y, a1);
            a2 = fmaf(w0[k].z, xv.z, a2);
            a3 = fmaf(w0[k].w, xv.w, a3);
            c0 = fmaf(w1[k].x, xv.x, c0);
            c1 = fmaf(w1[k].y, xv.y, c1);
            c2 = fmaf(w1[k].z, xv.z, c2);
            c3 = fmaf(w1[k].w, xv.w, c3);
        }
        float ra = (a0+a1) + (a2+a3) + bias0;
        float rb = (c0+c1) + (c2+c3) + bias1;
        if (cat == 1) { ra = softplus_f(ra); rb = softplus_f(rb); }
        const int tok = tok0 + tl;
        dst[tok*128 + l]      = ra;   // coalesced 256B
        dst[tok*128 + 64 + l] = rb;
    }

    if (cat == 0) {   // x_pool = x . w_pool (mean folded into weights)
        float wp = 0.f;
#pragma unroll 8
        for (int i = 0; i < DI; ++i) wp += W_in[i*DM + l];   // coalesced, L2-hot
        wp *= (1.0f/DI);
#pragma unroll
        for (int it = 0; it < PROJ_TOK/4; ++it) {
            const int tl = it*4 + w;
            float v = xl[tl*DM + l] * wp;
            v = wave64_sum(v);
            if (l == 0) ws[OFF_XPOOL + tok0 + tl] = v;
        }
    }
}

// ---- K2: exp-Abar + 8-step scan1 (R11, frozen). ----
__global__ __launch_bounds__(256) void k_abar_scan1(const float* __restrict__ A,
                                                    float* __restrict__ ws)
{
    __shared__ float psum[4][SEGLEN][64];   // 8 KB
    __shared__ float abL[SEGLEN][64];       // 2 KB
    const int tid  = threadIdx.x;
    const int lane = tid & 63;
    const int igrp = tid >> 6;
    const int g    = blockIdx.x >> 1;
    const int sh   = blockIdx.x & 1;
    const int s    = sh*64 + lane;
    const int t0   = g * SEGLEN;

    float areg[32];
#pragma unroll
    for (int i = 0; i < 32; ++i)
        areg[i] = A[(igrp*32 + i)*DSt + s] * 1.44269504f;

    const float* delta = ws + OFF_DELTA;
    float*       Abar  = ws + OFF_ABAR;

#pragma unroll
    for (int t = 0; t < SEGLEN; ++t) {
        const float* dv = delta + (t0 + t)*DI + igrp*32;
        float a0=0.f,a1=0.f,a2=0.f,a3=0.f;
#pragma unroll
        for (int q = 0; q < 8; ++q) {
            const float4 d4 = *(const float4*)(dv + 4*q);   // uniform bcast
            a0 += fast_exp2(d4.x * areg[4*q    ]);
            a1 += fast_exp2(d4.y * areg[4*q + 1]);
            a2 += fast_exp2(d4.z * areg[4*q + 2]);
            a3 += fast_exp2(d4.w * areg[4*q + 3]);
        }
        psum[igrp][t][lane] = (a0+a1) + (a2+a3);
    }
    __syncthreads();

#pragma unroll
    for (int it = tid; it < SEGLEN*64; it += 256) {
        const int t = it >> 6, l2 = it & 63;
        float v = (psum[0][t][l2] + psum[1][t][l2])
                + (psum[2][t][l2] + psum[3][t][l2]);
        v *= (1.0f/DI);
        abL[t][l2] = v;
        Abar[(t0 + t)*DSt + sh*64 + l2] = v;
    }
    __syncthreads();

    if (tid < 64) {
        const float* Bm    = ws + OFF_BM;
        const float* xpool = ws + OFF_XPOOL;
        float bx[SEGLEN];
#pragma unroll
        for (int t = 0; t < SEGLEN; ++t)
            bx[t] = Bm[(t0 + t)*DSt + s] * xpool[t0 + t];
        float h = 0.f, pr = 1.f;
#pragma unroll
        for (int t = 0; t < SEGLEN; ++t) {
            const float a = abL[t][lane];
            h = fmaf(a, h, bx[t]);
            pr *= a;
        }
        ws[OFF_HEND + g*DSt + s] = h;
        ws[OFF_P    + g*DSt + s] = pr;
    }
}

// ---- K3: y (R11, frozen). grid = 512 blocks x 128 threads ----
__global__ __launch_bounds__(128) void k_y(float* __restrict__ ws)
{
    __shared__ float prod[SEGLEN][132];
    const int s   = threadIdx.x;
    const int b   = blockIdx.x >> 7;
    const int seg = blockIdx.x & 127;
    const float* Abar  = ws + OFF_ABAR;
    const float* Bm    = ws + OFF_BM;
    const float* Cm    = ws + OFF_CM;
    const float* xpool = ws + OFF_XPOOL;
    const float* hend  = ws + OFF_HEND;
    const float* P     = ws + OFF_P;
    const int t0 = b*SL + seg*SEGLEN;

    float aA[SEGLEN], aB[SEGLEN], aC[SEGLEN];
#pragma unroll
    for (int t = 0; t < SEGLEN; ++t) {
        aA[t] = Abar[(t0 + t)*DSt + s];
        aB[t] = Bm[(t0 + t)*DSt + s] * xpool[t0 + t];
        aC[t] = Cm[(t0 + t)*DSt + s];
    }
    float h = 0.f;
#pragma unroll 8
    for (int j = 0; j < seg; ++j) {       // block-uniform trip count
        const int idx = (b*NSEG + j)*DSt + s;
        h = fmaf(P[idx], h, hend[idx]);
    }
#pragma unroll
    for (int t = 0; t < SEGLEN; ++t) {
        h = fmaf(aA[t], h, aB[t]);
        prod[t][s] = aC[t] * h;
    }
    __syncthreads();

    const int t = s >> 4, r = s & 15;     // 8 tokens x 16 lanes
    float4 u0 = *(const float4*)(&prod[t][r*8]);
    float4 u1 = *(const float4*)(&prod[t][r*8 + 4]);
    float acc = ((u0.x+u0.y) + (u0.z+u0.w)) + ((u1.x+u1.y) + (u1.z+u1.w));
#pragma unroll
    for (int m = 1; m <= 8; m <<= 1) acc += __shfl_xor(acc, m, 64);
    if (r == 0) ws[OFF_Y + b*SL + seg*SEGLEN + t] = acc;
}

// ---- K4: output (R11, frozen). grid = 1024 x 256; W4 from global repack ----
__global__ __launch_bounds__(256) void k_out(
    const float* __restrict__ x, const float* __restrict__ ln_w,
    const float* __restrict__ ln_b, const float* __restrict__ ws,
    float* __restrict__ out)
{
    __shared__ float vbuf[4][DI];
    const int tid = threadIdx.x;
    const int d   = tid & 63;
    const int wv  = tid >> 6;
    const int tok = blockIdx.x*4 + wv;

    const float* gate = ws + OFF_GATE;
    const float* y    = ws + OFF_Y;
    const float4* W4  = (const float4*)(ws + OFF_W4);

    const float yt = y[tok];
    const float g0 = gate[tok*DI + d];
    const float g1 = gate[tok*DI + 64 + d];
    vbuf[wv][d]      = yt * (g0 / (1.f + __expf(-g0)));
    vbuf[wv][64 + d] = yt * (g1 / (1.f + __expf(-g1)));
    __syncthreads();

    float ac0 = 0.f, ac1 = 0.f, ac2 = 0.f, ac3 = 0.f;
#pragma unroll 8
    for (int q = 0; q < 32; ++q) {
        const float4 wv4 = W4[q*64 + d];                     // coalesced 1KB
        const float4 vv  = *(const float4*)(&vbuf[wv][q*4]); // broadcast
        ac0 = fmaf(wv4.x, vv.x, ac0);
        ac1 = fmaf(wv4.y, vv.y, ac1);
        ac2 = fmaf(wv4.z, vv.z, ac2);
        ac3 = fmaf(wv4.w, vv.w, ac3);
    }
    const float z  = (ac0+ac1) + (ac2+ac3) + x[tok*DM + d];
    const float s1 = wave64_sum(z);
    const float s2 = wave64_sum(z*z);
    const float mu  = s1 * (1.f/64.f);
    const float var = s2 * (1.f/64.f) - mu*mu;
    out[tok*DM + d] = (z - mu) * rsqrtf(var + 1e-5f) * ln_w[d] + ln_b[d];
}

extern "C" void kernel_launch(void* const* d_in, const int* in_sizes, int n_in,
                              void* d_out, int out_size, void* d_ws, size_t ws_size,
                              hipStream_t stream) {
    const float* x       = (const float*)d_in[0];
    const float* W_in    = (const float*)d_in[1];
    const float* W_delta = (const float*)d_in[2];
    const float* b_delta = (const float*)d_in[3];
    const float* W_B     = (const float*)d_in[4];
    const float* b_B     = (const float*)d_in[5];
    const float* W_C     = (const float*)d_in[6];
    const float* b_C     = (const float*)d_in[7];
    const float* A       = (const float*)d_in[8];
    const float* W_out   = (const float*)d_in[9];
    const float* ln_w    = (const float*)d_in[10];
    const float* ln_b    = (const float*)d_in[11];
    float* out = (float*)d_out;
    float* ws  = (float*)d_ws;

    hipLaunchKernelGGL(k_proj, dim3(4*PROJ_TG + 1), dim3(256), 0, stream,
                       x, W_in, W_delta, b_delta, W_B, b_B, W_C, b_C, W_out, ws);
    hipLaunchKernelGGL(k_abar_scan1, dim3(2*NSEG_ALL), dim3(256), 0, stream, A, ws);
    hipLaunchKernelGGL(k_y,          dim3(NSEG_ALL),   dim3(128), 0, stream, ws);
    hipLaunchKernelGGL(k_out,        dim3(NTOK/4),     dim3(256), 0, stream,
                       x, ln_w, ln_b, ws, out);
}

// Round 16
// 48.473 us; speedup vs baseline: 3.4407x; 1.0230x over previous
//
#include <hip/hip_runtime.h>
#include <math.h>

#define NB   4
#define SL   1024
#define NTOK (NB*SL)      // 4096
#define DM   64
#define DI   128
#define DSt  128
#define SEGLEN 8
#define NSEG (SL/SEGLEN)  // 128
#define NSEG_ALL (NB*NSEG) // 512

// ---- workspace layout (float offsets) ----
#define OFF_GATE   0
#define OFF_DELTA  (OFF_GATE  + NTOK*DI)
#define OFF_BM     (OFF_DELTA + NTOK*DI)
#define OFF_CM     (OFF_BM    + NTOK*DSt)
#define OFF_XPOOL  (OFF_CM    + NTOK*DSt)
#define OFF_ABAR   (OFF_XPOOL + NTOK)
#define OFF_HEND   (OFF_ABAR  + NTOK*DSt)
#define OFF_P      (OFF_HEND  + NSEG_ALL*DSt)
#define OFF_W4     (OFF_P     + NSEG_ALL*DSt)   // 2048 float4

#define PROJ_TOK 16
#define PROJ_TG  (NTOK/PROJ_TOK)   // 256 token groups

static __device__ __forceinline__ float wave64_sum(float v) {
#pragma unroll
    for (int m = 32; m >= 1; m >>= 1) v += __shfl_xor(v, m, 64);
    return v;
}

static __device__ __forceinline__ float fast_exp2(float x) {
    float r;
    asm("v_exp_f32 %0, %1" : "=v"(r) : "v"(x));
    return r;
}

static __device__ __forceinline__ float softplus_f(float x) {
    return fmaxf(x, 0.f) + __logf(1.f + __expf(-fabsf(x)));
}

static __device__ __forceinline__ void pin4(float4& v) {
    asm volatile("" : "+v"(v.x), "+v"(v.y), "+v"(v.z), "+v"(v.w));
}

// async global->LDS 16B: linear LDS dest (wave base + lane*16), per-lane src
#if __has_builtin(__builtin_amdgcn_global_load_lds)
#define HAVE_GLL 1
static __device__ __forceinline__ void gload_lds16(const float4* g, float4* l) {
    __builtin_amdgcn_global_load_lds(
        (const __attribute__((address_space(1))) void*)g,
        (__attribute__((address_space(3))) void*)l,
        16, 0, 0);
}
#else
#define HAVE_GLL 0
#endif

// ---- K1: projections (R15, frozen). grid = 4x256 (+1 repack block). ----
__global__ __launch_bounds__(256, 2) void k_proj(
    const float* __restrict__ x, const float* __restrict__ W_in,
    const float* __restrict__ W_delta, const float* __restrict__ b_delta,
    const float* __restrict__ W_B, const float* __restrict__ b_B,
    const float* __restrict__ W_C, const float* __restrict__ b_C,
    const float* __restrict__ W_out, float* __restrict__ ws)
{
    __shared__ float  xl[PROJ_TOK*DM];   // 4 KB
    __shared__ float4 Wl[DI*16];         // 32 KB
    const int tid = threadIdx.x;

    if (blockIdx.x == 4*PROJ_TG) {       // tail: W_out repack W4[q*64+d]
        const float4* Wg = (const float4*)W_out;
        float4* W4 = (float4*)(ws + OFF_W4);
#pragma unroll
        for (int j = 0; j < 8; ++j) {
            const int f = tid + j*256;
            const int d = f >> 5, q = f & 31;
            W4[q*64 + d] = Wg[f];
        }
        return;
    }

    const int l   = tid & 63;
    const int w   = tid >> 6;
    const int cat = blockIdx.x >> 8;     // 0 gate, 1 delta, 2 B, 3 C
    const int tg  = blockIdx.x & 255;
    const int tok0 = tg * PROJ_TOK;

    const float* Wbase; const float* bias; float* dst;
    if      (cat == 0) { Wbase = W_in + DI*DM; bias = nullptr; dst = ws + OFF_GATE;  }
    else if (cat == 1) { Wbase = W_delta;      bias = b_delta; dst = ws + OFF_DELTA; }
    else if (cat == 2) { Wbase = W_B;          bias = b_B;     dst = ws + OFF_BM;    }
    else               { Wbase = W_C;          bias = b_C;     dst = ws + OFF_CM;    }

    {   // stage x tile (linear) + weight panel (src-swizzled), async to LDS
        const float4* xg = (const float4*)(x + tok0*DM);
        const float4* Wg = (const float4*)Wbase;
#if HAVE_GLL
        gload_lds16(xg + tid, ((float4*)xl) + tid);
#pragma unroll
        for (int j = 0; j < 8; ++j) {
            const int f   = tid + j*256;
            const int row = f >> 4, kk = f & 15;
            const int src = row*16 + (kk ^ (row & 15));   // involution
            gload_lds16(Wg + src, Wl + f);
        }
#else
        ((float4*)xl)[tid] = xg[tid];
#pragma unroll
        for (int j = 0; j < 8; ++j) {
            const int f = tid + j*256;
            const int row = f >> 4, k = f & 15;
            Wl[row*16 + (k ^ (row & 15))] = Wg[f];
        }
#endif
    }
    __syncthreads();

    float4 w0[16], w1[16];
#pragma unroll
    for (int k = 0; k < 16; ++k) {
        w0[k] = Wl[l*16      + (k ^ (l & 15))];
        w1[k] = Wl[(l+64)*16 + (k ^ (l & 15))];
    }
#pragma unroll
    for (int k = 0; k < 16; ++k) { pin4(w0[k]); pin4(w1[k]); }

    float bias0 = 0.f, bias1 = 0.f;
    if (bias) { bias0 = bias[l]; bias1 = bias[l+64]; }

#pragma unroll
    for (int it = 0; it < PROJ_TOK/4; ++it) {
        const int tl = it*4 + w;
        float a0=0.f,a1=0.f,a2=0.f,a3=0.f, c0=0.f,c1=0.f,c2=0.f,c3=0.f;
#pragma unroll
        for (int k = 0; k < 16; ++k) {
            const float4 xv = *(const float4*)(xl + tl*DM + 4*k);  // broadcast
            a0 = fmaf(w0[k].x, xv.x, a0);
            a1 = fmaf(w0[k].y, xv.y, a1);
            a2 = fmaf(w0[k].z, xv.z, a2);
            a3 = fmaf(w0[k].w, xv.w, a3);
            c0 = fmaf(w1[k].x, xv.x, c0);
            c1 = fmaf(w1[k].y, xv.y, c1);
            c2 = fmaf(w1[k].z, xv.z, c2);
            c3 = fmaf(w1[k].w, xv.w, c3);
        }
        float ra = (a0+a1) + (a2+a3) + bias0;
        float rb = (c0+c1) + (c2+c3) + bias1;
        if (cat == 1) { ra = softplus_f(ra); rb = softplus_f(rb); }
        const int tok = tok0 + tl;
        dst[tok*128 + l]      = ra;   // coalesced 256B
        dst[tok*128 + 64 + l] = rb;
    }

    if (cat == 0) {   // x_pool = x . w_pool
        float wp = 0.f;
#pragma unroll 8
        for (int i = 0; i < DI; ++i) wp += W_in[i*DM + l];
        wp *= (1.0f/DI);
#pragma unroll
        for (int it = 0; it < PROJ_TOK/4; ++it) {
            const int tl = it*4 + w;
            float v = xl[tl*DM + l] * wp;
            v = wave64_sum(v);
            if (l == 0) ws[OFF_XPOOL + tok0 + tl] = v;
        }
    }
}

// ---- K2: exp-Abar + 8-step scan1 (R11/R15, frozen). ----
__global__ __launch_bounds__(256) void k_abar_scan1(const float* __restrict__ A,
                                                    float* __restrict__ ws)
{
    __shared__ float psum[4][SEGLEN][64];   // 8 KB
    __shared__ float abL[SEGLEN][64];       // 2 KB
    const int tid  = threadIdx.x;
    const int lane = tid & 63;
    const int igrp = tid >> 6;
    const int g    = blockIdx.x >> 1;
    const int sh   = blockIdx.x & 1;
    const int s    = sh*64 + lane;
    const int t0   = g * SEGLEN;

    float areg[32];
#pragma unroll
    for (int i = 0; i < 32; ++i)
        areg[i] = A[(igrp*32 + i)*DSt + s] * 1.44269504f;

    const float* delta = ws + OFF_DELTA;
    float*       Abar  = ws + OFF_ABAR;

#pragma unroll
    for (int t = 0; t < SEGLEN; ++t) {
        const float* dv = delta + (t0 + t)*DI + igrp*32;
        float a0=0.f,a1=0.f,a2=0.f,a3=0.f;
#pragma unroll
        for (int q = 0; q < 8; ++q) {
            const float4 d4 = *(const float4*)(dv + 4*q);   // uniform bcast
            a0 += fast_exp2(d4.x * areg[4*q    ]);
            a1 += fast_exp2(d4.y * areg[4*q + 1]);
            a2 += fast_exp2(d4.z * areg[4*q + 2]);
            a3 += fast_exp2(d4.w * areg[4*q + 3]);
        }
        psum[igrp][t][lane] = (a0+a1) + (a2+a3);
    }
    __syncthreads();

#pragma unroll
    for (int it = tid; it < SEGLEN*64; it += 256) {
        const int t = it >> 6, l2 = it & 63;
        float v = (psum[0][t][l2] + psum[1][t][l2])
                + (psum[2][t][l2] + psum[3][t][l2]);
        v *= (1.0f/DI);
        abL[t][l2] = v;
        Abar[(t0 + t)*DSt + sh*64 + l2] = v;
    }
    __syncthreads();

    if (tid < 64) {
        const float* Bm    = ws + OFF_BM;
        const float* xpool = ws + OFF_XPOOL;
        float bx[SEGLEN];
#pragma unroll
        for (int t = 0; t < SEGLEN; ++t)
            bx[t] = Bm[(t0 + t)*DSt + s] * xpool[t0 + t];
        float h = 0.f, pr = 1.f;
#pragma unroll
        for (int t = 0; t < SEGLEN; ++t) {
            const float a = abL[t][lane];
            h = fmaf(a, h, bx[t]);
            pr *= a;
        }
        ws[OFF_HEND + g*DSt + s] = h;
        ws[OFF_P    + g*DSt + s] = pr;
    }
}

// ---- K3: fused y + output, 256 threads. grid = 512 blocks (1 segment each).
// Pre-phase: all 256 threads issue gate/x/ln loads (land under phase A).
// Phase A (tid<128): stitch + rescan + y-reduce -> y_lds.
// Phase B: 4 waves x 2 tokens (same per-token wave throughput as k_out);
// W4 from global repack (coalesced, L2-hot); vbuf wave-private. ----
__global__ __launch_bounds__(256) void k_tail(
    const float* __restrict__ x, const float* __restrict__ ln_w,
    const float* __restrict__ ln_b, const float* __restrict__ ws,
    float* __restrict__ out)
{
    __shared__ float prod[SEGLEN][132];
    __shared__ float y_lds[SEGLEN];
    __shared__ float vbuf[4][DI];

    const int tid = threadIdx.x;
    const int b   = blockIdx.x >> 7;
    const int seg = blockIdx.x & 127;
    const int t0  = b*SL + seg*SEGLEN;
    const int d   = tid & 63;
    const int wv  = tid >> 6;

    // pre-phase: issue phase-B operand loads (hide under phase A)
    const float* gate = ws + OFF_GATE;
    float g0[2], g1[2], xres[2];
#pragma unroll
    for (int jt = 0; jt < 2; ++jt) {
        const int tok = t0 + wv*2 + jt;
        g0[jt]   = gate[tok*DI + d];
        g1[jt]   = gate[tok*DI + 64 + d];
        xres[jt] = x[tok*DM + d];
    }
    const float lw = ln_w[d], lb = ln_b[d];

    // phase A on first 128 threads
    if (tid < 128) {
        const int s = tid;
        const float* Abar  = ws + OFF_ABAR;
        const float* Bm    = ws + OFF_BM;
        const float* Cm    = ws + OFF_CM;
        const float* xpool = ws + OFF_XPOOL;
        const float* hend  = ws + OFF_HEND;
        const float* P     = ws + OFF_P;

        float aA[SEGLEN], aB[SEGLEN], aC[SEGLEN];
#pragma unroll
        for (int t = 0; t < SEGLEN; ++t) {
            aA[t] = Abar[(t0 + t)*DSt + s];
            aB[t] = Bm[(t0 + t)*DSt + s] * xpool[t0 + t];
            aC[t] = Cm[(t0 + t)*DSt + s];
        }
        float h = 0.f;
#pragma unroll 8
        for (int j = 0; j < seg; ++j) {   // block-uniform trip count
            const int idx = (b*NSEG + j)*DSt + s;
            h = fmaf(P[idx], h, hend[idx]);
        }
#pragma unroll
        for (int t = 0; t < SEGLEN; ++t) {
            h = fmaf(aA[t], h, aB[t]);
            prod[t][s] = aC[t] * h;
        }
    }
    __syncthreads();

    if (tid < 128) {   // y reduce: 16 lanes per token
        const int t = tid >> 4, r = tid & 15;
        float4 u0 = *(const float4*)(&prod[t][r*8]);
        float4 u1 = *(const float4*)(&prod[t][r*8 + 4]);
        float acc = ((u0.x+u0.y) + (u0.z+u0.w)) + ((u1.x+u1.y) + (u1.z+u1.w));
#pragma unroll
        for (int m = 1; m <= 8; m <<= 1) acc += __shfl_xor(acc, m, 64);
        if (r == 0) y_lds[t] = acc;
    }
    __syncthreads();

    // phase B: 4 waves x 2 tokens; vbuf wave-private -> no barriers
    const float4* W4 = (const float4*)(ws + OFF_W4);
#pragma unroll
    for (int jt = 0; jt < 2; ++jt) {
        const int tl  = wv*2 + jt;
        const int tok = t0 + tl;
        const float yt = y_lds[tl];
        vbuf[wv][d]      = yt * (g0[jt] / (1.f + __expf(-g0[jt])));
        vbuf[wv][64 + d] = yt * (g1[jt] / (1.f + __expf(-g1[jt])));

        float ac0 = 0.f, ac1 = 0.f, ac2 = 0.f, ac3 = 0.f;
#pragma unroll 8
        for (int q = 0; q < 32; ++q) {
            const float4 wv4 = W4[q*64 + d];                   // coalesced 1KB
            const float4 vv  = *(const float4*)(&vbuf[wv][q*4]); // broadcast
            ac0 = fmaf(wv4.x, vv.x, ac0);
            ac1 = fmaf(wv4.y, vv.y, ac1);
            ac2 = fmaf(wv4.z, vv.z, ac2);
            ac3 = fmaf(wv4.w, vv.w, ac3);
        }
        const float z  = (ac0+ac1) + (ac2+ac3) + xres[jt];
        const float s1 = wave64_sum(z);
        const float s2 = wave64_sum(z*z);
        const float mu  = s1 * (1.f/64.f);
        const float var = s2 * (1.f/64.f) - mu*mu;
        out[tok*DM + d] = (z - mu) * rsqrtf(var + 1e-5f) * lw + lb;
    }
}

extern "C" void kernel_launch(void* const* d_in, const int* in_sizes, int n_in,
                              void* d_out, int out_size, void* d_ws, size_t ws_size,
                              hipStream_t stream) {
    const float* x       = (const float*)d_in[0];
    const float* W_in    = (const float*)d_in[1];
    const float* W_delta = (const float*)d_in[2];
    const float* b_delta = (const float*)d_in[3];
    const float* W_B     = (const float*)d_in[4];
    const float* b_B     = (const float*)d_in[5];
    const float* W_C     = (const float*)d_in[6];
    const float* b_C     = (const float*)d_in[7];
    const float* A       = (const float*)d_in[8];
    const float* W_out   = (const float*)d_in[9];
    const float* ln_w    = (const float*)d_in[10];
    const float* ln_b    = (const float*)d_in[11];
    float* out = (float*)d_out;
    float* ws  = (float*)d_ws;

    hipLaunchKernelGGL(k_proj, dim3(4*PROJ_TG + 1), dim3(256), 0, stream,
                       x, W_in, W_delta, b_delta, W_B, b_B, W_C, b_C, W_out, ws);
    hipLaunchKernelGGL(k_abar_scan1, dim3(2*NSEG_ALL), dim3(256), 0, stream, A, ws);
    hipLaunchKernelGGL(k_tail,       dim3(NSEG_ALL),   dim3(256), 0, stream,
                       x, ln_w, ln_b, ws, out);
}

// Round 17
// 46.002 us; speedup vs baseline: 3.6255x; 1.0537x over previous
//
#include <hip/hip_runtime.h>
#include <math.h>

#define NB   4
#define SL   1024
#define NTOK (NB*SL)      // 4096
#define DM   64
#define DI   128
#define DSt  128
#define SEGLEN 8
#define NSEG (SL/SEGLEN)  // 128
#define NSEG_ALL (NB*NSEG) // 512

// ---- workspace layout (float offsets) ----
#define OFF_GATE   0
#define OFF_DELTA  (OFF_GATE  + NTOK*DI)
#define OFF_BM     (OFF_DELTA + NTOK*DI)
#define OFF_CM     (OFF_BM    + NTOK*DSt)
#define OFF_XPOOL  (OFF_CM    + NTOK*DSt)
#define OFF_ABAR   (OFF_XPOOL + NTOK)
#define OFF_HEND   (OFF_ABAR  + NTOK*DSt)
#define OFF_P      (OFF_HEND  + NSEG_ALL*DSt)
#define OFF_W4     (OFF_P     + NSEG_ALL*DSt)   // 2048 float4

#define PROJ_TOK 16
#define PROJ_TG  (NTOK/PROJ_TOK)   // 256 token groups

static __device__ __forceinline__ float wave64_sum(float v) {
#pragma unroll
    for (int m = 32; m >= 1; m >>= 1) v += __shfl_xor(v, m, 64);
    return v;
}

static __device__ __forceinline__ float fast_exp2(float x) {
    float r;
    asm("v_exp_f32 %0, %1" : "=v"(r) : "v"(x));
    return r;
}

static __device__ __forceinline__ float softplus_f(float x) {
    return fmaxf(x, 0.f) + __logf(1.f + __expf(-fabsf(x)));
}

static __device__ __forceinline__ void pin4(float4& v) {
    asm volatile("" : "+v"(v.x), "+v"(v.y), "+v"(v.z), "+v"(v.w));
}

// async global->LDS 16B: linear LDS dest (wave base + lane*16), per-lane src
#if __has_builtin(__builtin_amdgcn_global_load_lds)
#define HAVE_GLL 1
static __device__ __forceinline__ void gload_lds16(const float4* g, float4* l) {
    __builtin_amdgcn_global_load_lds(
        (const __attribute__((address_space(1))) void*)g,
        (__attribute__((address_space(3))) void*)l,
        16, 0, 0);
}
#else
#define HAVE_GLL 0
#endif

// ---- K1: projections. grid = 4 cats x 256 token-groups (+1 repack block).
// v3: x-broadcasts moved OFF the LDS pipe — read from global at
// readfirstlane-uniformed addresses (L1/sL1-hot 4KB tile). LDS holds only
// the weight panel (src-swizzled async staging + conflict-free frag reads).
__global__ __launch_bounds__(256, 2) void k_proj(
    const float* __restrict__ x, const float* __restrict__ W_in,
    const float* __restrict__ W_delta, const float* __restrict__ b_delta,
    const float* __restrict__ W_B, const float* __restrict__ b_B,
    const float* __restrict__ W_C, const float* __restrict__ b_C,
    const float* __restrict__ W_out, float* __restrict__ ws)
{
    __shared__ float4 Wl[DI*16];         // 32 KB
    const int tid = threadIdx.x;

    if (blockIdx.x == 4*PROJ_TG) {       // tail: W_out repack W4[q*64+d]
        const float4* Wg = (const float4*)W_out;
        float4* W4 = (float4*)(ws + OFF_W4);
#pragma unroll
        for (int j = 0; j < 8; ++j) {
            const int f = tid + j*256;
            const int d = f >> 5, q = f & 31;
            W4[q*64 + d] = Wg[f];
        }
        return;
    }

    const int l   = tid & 63;
    const int w   = tid >> 6;
    const int cat = blockIdx.x >> 8;     // 0 gate, 1 delta, 2 B, 3 C
    const int tg  = blockIdx.x & 255;
    const int tok0 = tg * PROJ_TOK;

    const float* Wbase; const float* bias; float* dst;
    if      (cat == 0) { Wbase = W_in + DI*DM; bias = nullptr; dst = ws + OFF_GATE;  }
    else if (cat == 1) { Wbase = W_delta;      bias = b_delta; dst = ws + OFF_DELTA; }
    else if (cat == 2) { Wbase = W_B;          bias = b_B;     dst = ws + OFF_BM;    }
    else               { Wbase = W_C;          bias = b_C;     dst = ws + OFF_CM;    }

    {   // stage weight panel (2048 f4, src-swizzled) async to LDS
        const float4* Wg = (const float4*)Wbase;
#if HAVE_GLL
#pragma unroll
        for (int j = 0; j < 8; ++j) {
            const int f   = tid + j*256;
            const int row = f >> 4, kk = f & 15;
            const int src = row*16 + (kk ^ (row & 15));   // involution
            gload_lds16(Wg + src, Wl + f);
        }
#else
#pragma unroll
        for (int j = 0; j < 8; ++j) {
            const int f = tid + j*256;
            const int row = f >> 4, k = f & 15;
            Wl[row*16 + (k ^ (row & 15))] = Wg[f];
        }
#endif
    }
    __syncthreads();

    float4 w0[16], w1[16];
#pragma unroll
    for (int k = 0; k < 16; ++k) {
        w0[k] = Wl[l*16      + (k ^ (l & 15))];
        w1[k] = Wl[(l+64)*16 + (k ^ (l & 15))];
    }
#pragma unroll
    for (int k = 0; k < 16; ++k) { pin4(w0[k]); pin4(w1[k]); }

    float bias0 = 0.f, bias1 = 0.f;
    if (bias) { bias0 = bias[l]; bias1 = bias[l+64]; }

#pragma unroll
    for (int it = 0; it < PROJ_TOK/4; ++it) {
        // wave-uniform token -> uniform x addresses -> scalar/VMEM path,
        // zero LDS-pipe traffic for the broadcasts
        const int tlu = __builtin_amdgcn_readfirstlane(it*4 + w);
        const float4* xt = (const float4*)(x + (tok0 + tlu)*DM);
        float a0=0.f,a1=0.f,a2=0.f,a3=0.f, c0=0.f,c1=0.f,c2=0.f,c3=0.f;
#pragma unroll
        for (int k = 0; k < 16; ++k) {
            const float4 xv = xt[k];          // uniform address
            a0 = fmaf(w0[k].x, xv.x, a0);
            a1 = fmaf(w0[k].y, xv.y, a1);
            a2 = fmaf(w0[k].z, xv.z, a2);
            a3 = fmaf(w0[k].w, xv.w, a3);
            c0 = fmaf(w1[k].x, xv.x, c0);
            c1 = fmaf(w1[k].y, xv.y, c1);
            c2 = fmaf(w1[k].z, xv.z, c2);
            c3 = fmaf(w1[k].w, xv.w, c3);
        }
        float ra = (a0+a1) + (a2+a3) + bias0;
        float rb = (c0+c1) + (c2+c3) + bias1;
        if (cat == 1) { ra = softplus_f(ra); rb = softplus_f(rb); }
        const int tok = tok0 + tlu;
        dst[tok*128 + l]      = ra;   // coalesced 256B
        dst[tok*128 + 64 + l] = rb;
    }

    if (cat == 0) {   // x_pool = x . w_pool (coalesced global reads, L1-hot)
        float wp = 0.f;
#pragma unroll 8
        for (int i = 0; i < DI; ++i) wp += W_in[i*DM + l];
        wp *= (1.0f/DI);
#pragma unroll
        for (int it = 0; it < PROJ_TOK/4; ++it) {
            const int tl = it*4 + w;
            float v = x[(tok0 + tl)*DM + l] * wp;
            v = wave64_sum(v);
            if (l == 0) ws[OFF_XPOOL + tok0 + tl] = v;
        }
    }
}

// ---- K2: exp-Abar + 8-step scan1 (frozen). ----
__global__ __launch_bounds__(256) void k_abar_scan1(const float* __restrict__ A,
                                                    float* __restrict__ ws)
{
    __shared__ float psum[4][SEGLEN][64];   // 8 KB
    __shared__ float abL[SEGLEN][64];       // 2 KB
    const int tid  = threadIdx.x;
    const int lane = tid & 63;
    const int igrp = tid >> 6;
    const int g    = blockIdx.x >> 1;
    const int sh   = blockIdx.x & 1;
    const int s    = sh*64 + lane;
    const int t0   = g * SEGLEN;

    float areg[32];
#pragma unroll
    for (int i = 0; i < 32; ++i)
        areg[i] = A[(igrp*32 + i)*DSt + s] * 1.44269504f;

    const float* delta = ws + OFF_DELTA;
    float*       Abar  = ws + OFF_ABAR;

#pragma unroll
    for (int t = 0; t < SEGLEN; ++t) {
        const float* dv = delta + (t0 + t)*DI + igrp*32;
        float a0=0.f,a1=0.f,a2=0.f,a3=0.f;
#pragma unroll
        for (int q = 0; q < 8; ++q) {
            const float4 d4 = *(const float4*)(dv + 4*q);   // uniform bcast
            a0 += fast_exp2(d4.x * areg[4*q    ]);
            a1 += fast_exp2(d4.y * areg[4*q + 1]);
            a2 += fast_exp2(d4.z * areg[4*q + 2]);
            a3 += fast_exp2(d4.w * areg[4*q + 3]);
        }
        psum[igrp][t][lane] = (a0+a1) + (a2+a3);
    }
    __syncthreads();

#pragma unroll
    for (int it = tid; it < SEGLEN*64; it += 256) {
        const int t = it >> 6, l2 = it & 63;
        float v = (psum[0][t][l2] + psum[1][t][l2])
                + (psum[2][t][l2] + psum[3][t][l2]);
        v *= (1.0f/DI);
        abL[t][l2] = v;
        Abar[(t0 + t)*DSt + sh*64 + l2] = v;
    }
    __syncthreads();

    if (tid < 64) {
        const float* Bm    = ws + OFF_BM;
        const float* xpool = ws + OFF_XPOOL;
        float bx[SEGLEN];
#pragma unroll
        for (int t = 0; t < SEGLEN; ++t)
            bx[t] = Bm[(t0 + t)*DSt + s] * xpool[t0 + t];
        float h = 0.f, pr = 1.f;
#pragma unroll
        for (int t = 0; t < SEGLEN; ++t) {
            const float a = abL[t][lane];
            h = fmaf(a, h, bx[t]);
            pr *= a;
        }
        ws[OFF_HEND + g*DSt + s] = h;
        ws[OFF_P    + g*DSt + s] = pr;
    }
}

// ---- K3: fused y + output, 256 threads (R16, frozen). ----
__global__ __launch_bounds__(256) void k_tail(
    const float* __restrict__ x, const float* __restrict__ ln_w,
    const float* __restrict__ ln_b, const float* __restrict__ ws,
    float* __restrict__ out)
{
    __shared__ float prod[SEGLEN][132];
    __shared__ float y_lds[SEGLEN];
    __shared__ float vbuf[4][DI];

    const int tid = threadIdx.x;
    const int b   = blockIdx.x >> 7;
    const int seg = blockIdx.x & 127;
    const int t0  = b*SL + seg*SEGLEN;
    const int d   = tid & 63;
    const int wv  = tid >> 6;

    // pre-phase: issue phase-B operand loads (hide under phase A)
    const float* gate = ws + OFF_GATE;
    float g0[2], g1[2], xres[2];
#pragma unroll
    for (int jt = 0; jt < 2; ++jt) {
        const int tok = t0 + wv*2 + jt;
        g0[jt]   = gate[tok*DI + d];
        g1[jt]   = gate[tok*DI + 64 + d];
        xres[jt] = x[tok*DM + d];
    }
    const float lw = ln_w[d], lb = ln_b[d];

    if (tid < 128) {
        const int s = tid;
        const float* Abar  = ws + OFF_ABAR;
        const float* Bm    = ws + OFF_BM;
        const float* Cm    = ws + OFF_CM;
        const float* xpool = ws + OFF_XPOOL;
        const float* hend  = ws + OFF_HEND;
        const float* P     = ws + OFF_P;

        float aA[SEGLEN], aB[SEGLEN], aC[SEGLEN];
#pragma unroll
        for (int t = 0; t < SEGLEN; ++t) {
            aA[t] = Abar[(t0 + t)*DSt + s];
            aB[t] = Bm[(t0 + t)*DSt + s] * xpool[t0 + t];
            aC[t] = Cm[(t0 + t)*DSt + s];
        }
        float h = 0.f;
#pragma unroll 8
        for (int j = 0; j < seg; ++j) {   // block-uniform trip count
            const int idx = (b*NSEG + j)*DSt + s;
            h = fmaf(P[idx], h, hend[idx]);
        }
#pragma unroll
        for (int t = 0; t < SEGLEN; ++t) {
            h = fmaf(aA[t], h, aB[t]);
            prod[t][s] = aC[t] * h;
        }
    }
    __syncthreads();

    if (tid < 128) {   // y reduce: 16 lanes per token
        const int t = tid >> 4, r = tid & 15;
        float4 u0 = *(const float4*)(&prod[t][r*8]);
        float4 u1 = *(const float4*)(&prod[t][r*8 + 4]);
        float acc = ((u0.x+u0.y) + (u0.z+u0.w)) + ((u1.x+u1.y) + (u1.z+u1.w));
#pragma unroll
        for (int m = 1; m <= 8; m <<= 1) acc += __shfl_xor(acc, m, 64);
        if (r == 0) y_lds[t] = acc;
    }
    __syncthreads();

    // phase B: 4 waves x 2 tokens; vbuf wave-private -> no barriers
    const float4* W4 = (const float4*)(ws + OFF_W4);
#pragma unroll
    for (int jt = 0; jt < 2; ++jt) {
        const int tl  = wv*2 + jt;
        const int tok = t0 + tl;
        const float yt = y_lds[tl];
        vbuf[wv][d]      = yt * (g0[jt] / (1.f + __expf(-g0[jt])));
        vbuf[wv][64 + d] = yt * (g1[jt] / (1.f + __expf(-g1[jt])));

        float ac0 = 0.f, ac1 = 0.f, ac2 = 0.f, ac3 = 0.f;
#pragma unroll 8
        for (int q = 0; q < 32; ++q) {
            const float4 wv4 = W4[q*64 + d];                   // coalesced 1KB
            const float4 vv  = *(const float4*)(&vbuf[wv][q*4]); // broadcast
            ac0 = fmaf(wv4.x, vv.x, ac0);
            ac1 = fmaf(wv4.y, vv.y, ac1);
            ac2 = fmaf(wv4.z, vv.z, ac2);
            ac3 = fmaf(wv4.w, vv.w, ac3);
        }
        const float z  = (ac0+ac1) + (ac2+ac3) + xres[jt];
        const float s1 = wave64_sum(z);
        const float s2 = wave64_sum(z*z);
        const float mu  = s1 * (1.f/64.f);
        const float var = s2 * (1.f/64.f) - mu*mu;
        out[tok*DM + d] = (z - mu) * rsqrtf(var + 1e-5f) * lw + lb;
    }
}

extern "C" void kernel_launch(void* const* d_in, const int* in_sizes, int n_in,
                              void* d_out, int out_size, void* d_ws, size_t ws_size,
                              hipStream_t stream) {
    const float* x       = (const float*)d_in[0];
    const float* W_in    = (const float*)d_in[1];
    const float* W_delta = (const float*)d_in[2];
    const float* b_delta = (const float*)d_in[3];
    const float* W_B     = (const float*)d_in[4];
    const float* b_B     = (const float*)d_in[5];
    const float* W_C     = (const float*)d_in[6];
    const float* b_C     = (const float*)d_in[7];
    const float* A       = (const float*)d_in[8];
    const float* W_out   = (const float*)d_in[9];
    const float* ln_w    = (const float*)d_in[10];
    const float* ln_b    = (const float*)d_in[11];
    float* out = (float*)d_out;
    float* ws  = (float*)d_ws;

    hipLaunchKernelGGL(k_proj, dim3(4*PROJ_TG + 1), dim3(256), 0, stream,
                       x, W_in, W_delta, b_delta, W_B, b_B, W_C, b_C, W_out, ws);
    hipLaunchKernelGGL(k_abar_scan1, dim3(2*NSEG_ALL), dim3(256), 0, stream, A, ws);
    hipLaunchKernelGGL(k_tail,       dim3(NSEG_ALL),   dim3(256), 0, stream,
                       x, ln_w, ln_b, ws, out);
}

// Round 18
// 43.023 us; speedup vs baseline: 3.8766x; 1.0693x over previous
//
#include <hip/hip_runtime.h>
#include <math.h>

#define NB   4
#define SL   1024
#define NTOK (NB*SL)      // 4096
#define DM   64
#define DI   128
#define DSt  128
#define SEGLEN 8
#define NSEG (SL/SEGLEN)  // 128
#define NSEG_ALL (NB*NSEG) // 512

// ---- workspace layout (float offsets) ----
#define OFF_GATE   0
#define OFF_DELTA  (OFF_GATE  + NTOK*DI)
#define OFF_BM     (OFF_DELTA + NTOK*DI)
#define OFF_CM     (OFF_BM    + NTOK*DSt)
#define OFF_XPOOL  (OFF_CM    + NTOK*DSt)
#define OFF_ABAR   (OFF_XPOOL + NTOK)
#define OFF_HEND   (OFF_ABAR  + NTOK*DSt)
#define OFF_P      (OFF_HEND  + NSEG_ALL*DSt)
#define OFF_W4     (OFF_P     + NSEG_ALL*DSt)   // 2048 float4

#define PROJ_TOK 16
#define PROJ_TG  (NTOK/PROJ_TOK)   // 256 token groups

static __device__ __forceinline__ float wave64_sum(float v) {
#pragma unroll
    for (int m = 32; m >= 1; m >>= 1) v += __shfl_xor(v, m, 64);
    return v;
}

static __device__ __forceinline__ float fast_exp2(float x) {
    float r;
    asm("v_exp_f32 %0, %1" : "=v"(r) : "v"(x));
    return r;
}

static __device__ __forceinline__ float softplus_f(float x) {
    return fmaxf(x, 0.f) + __logf(1.f + __expf(-fabsf(x)));
}

static __device__ __forceinline__ void pin4(float4& v) {
    asm volatile("" : "+v"(v.x), "+v"(v.y), "+v"(v.z), "+v"(v.w));
}

// async global->LDS 16B: linear LDS dest (wave base + lane*16), per-lane src
#if __has_builtin(__builtin_amdgcn_global_load_lds)
#define HAVE_GLL 1
static __device__ __forceinline__ void gload_lds16(const float4* g, float4* l) {
    __builtin_amdgcn_global_load_lds(
        (const __attribute__((address_space(1))) void*)g,
        (__attribute__((address_space(3))) void*)l,
        16, 0, 0);
}
#else
#define HAVE_GLL 0
#endif

// ---- K1: projections (R17, frozen). grid = 4x256 (+1 repack block). ----
__global__ __launch_bounds__(256, 2) void k_proj(
    const float* __restrict__ x, const float* __restrict__ W_in,
    const float* __restrict__ W_delta, const float* __restrict__ b_delta,
    const float* __restrict__ W_B, const float* __restrict__ b_B,
    const float* __restrict__ W_C, const float* __restrict__ b_C,
    const float* __restrict__ W_out, float* __restrict__ ws)
{
    __shared__ float4 Wl[DI*16];         // 32 KB
    const int tid = threadIdx.x;

    if (blockIdx.x == 4*PROJ_TG) {       // tail: W_out repack W4[q*64+d]
        const float4* Wg = (const float4*)W_out;
        float4* W4 = (float4*)(ws + OFF_W4);
#pragma unroll
        for (int j = 0; j < 8; ++j) {
            const int f = tid + j*256;
            const int d = f >> 5, q = f & 31;
            W4[q*64 + d] = Wg[f];
        }
        return;
    }

    const int l   = tid & 63;
    const int w   = tid >> 6;
    const int cat = blockIdx.x >> 8;     // 0 gate, 1 delta, 2 B, 3 C
    const int tg  = blockIdx.x & 255;
    const int tok0 = tg * PROJ_TOK;

    const float* Wbase; const float* bias; float* dst;
    if      (cat == 0) { Wbase = W_in + DI*DM; bias = nullptr; dst = ws + OFF_GATE;  }
    else if (cat == 1) { Wbase = W_delta;      bias = b_delta; dst = ws + OFF_DELTA; }
    else if (cat == 2) { Wbase = W_B;          bias = b_B;     dst = ws + OFF_BM;    }
    else               { Wbase = W_C;          bias = b_C;     dst = ws + OFF_CM;    }

    {   // stage weight panel (2048 f4, src-swizzled) async to LDS
        const float4* Wg = (const float4*)Wbase;
#if HAVE_GLL
#pragma unroll
        for (int j = 0; j < 8; ++j) {
            const int f   = tid + j*256;
            const int row = f >> 4, kk = f & 15;
            const int src = row*16 + (kk ^ (row & 15));   // involution
            gload_lds16(Wg + src, Wl + f);
        }
#else
#pragma unroll
        for (int j = 0; j < 8; ++j) {
            const int f = tid + j*256;
            const int row = f >> 4, k = f & 15;
            Wl[row*16 + (k ^ (row & 15))] = Wg[f];
        }
#endif
    }
    __syncthreads();

    float4 w0[16], w1[16];
#pragma unroll
    for (int k = 0; k < 16; ++k) {
        w0[k] = Wl[l*16      + (k ^ (l & 15))];
        w1[k] = Wl[(l+64)*16 + (k ^ (l & 15))];
    }
#pragma unroll
    for (int k = 0; k < 16; ++k) { pin4(w0[k]); pin4(w1[k]); }

    float bias0 = 0.f, bias1 = 0.f;
    if (bias) { bias0 = bias[l]; bias1 = bias[l+64]; }

#pragma unroll
    for (int it = 0; it < PROJ_TOK/4; ++it) {
        const int tlu = __builtin_amdgcn_readfirstlane(it*4 + w);
        const float4* xt = (const float4*)(x + (tok0 + tlu)*DM);
        float a0=0.f,a1=0.f,a2=0.f,a3=0.f, c0=0.f,c1=0.f,c2=0.f,c3=0.f;
#pragma unroll
        for (int k = 0; k < 16; ++k) {
            const float4 xv = xt[k];          // uniform address, off LDS pipe
            a0 = fmaf(w0[k].x, xv.x, a0);
            a1 = fmaf(w0[k].y, xv.y, a1);
            a2 = fmaf(w0[k].z, xv.z, a2);
            a3 = fmaf(w0[k].w, xv.w, a3);
            c0 = fmaf(w1[k].x, xv.x, c0);
            c1 = fmaf(w1[k].y, xv.y, c1);
            c2 = fmaf(w1[k].z, xv.z, c2);
            c3 = fmaf(w1[k].w, xv.w, c3);
        }
        float ra = (a0+a1) + (a2+a3) + bias0;
        float rb = (c0+c1) + (c2+c3) + bias1;
        if (cat == 1) { ra = softplus_f(ra); rb = softplus_f(rb); }
        const int tok = tok0 + tlu;
        dst[tok*128 + l]      = ra;   // coalesced 256B
        dst[tok*128 + 64 + l] = rb;
    }

    if (cat == 0) {   // x_pool = x . w_pool
        float wp = 0.f;
#pragma unroll 8
        for (int i = 0; i < DI; ++i) wp += W_in[i*DM + l];
        wp *= (1.0f/DI);
#pragma unroll
        for (int it = 0; it < PROJ_TOK/4; ++it) {
            const int tl = it*4 + w;
            float v = x[(tok0 + tl)*DM + l] * wp;
            v = wave64_sum(v);
            if (l == 0) ws[OFF_XPOOL + tok0 + tl] = v;
        }
    }
}

// ---- K2: exp-Abar + 8-step scan1 (frozen). ----
__global__ __launch_bounds__(256) void k_abar_scan1(const float* __restrict__ A,
                                                    float* __restrict__ ws)
{
    __shared__ float psum[4][SEGLEN][64];   // 8 KB
    __shared__ float abL[SEGLEN][64];       // 2 KB
    const int tid  = threadIdx.x;
    const int lane = tid & 63;
    const int igrp = tid >> 6;
    const int g    = blockIdx.x >> 1;
    const int sh   = blockIdx.x & 1;
    const int s    = sh*64 + lane;
    const int t0   = g * SEGLEN;

    float areg[32];
#pragma unroll
    for (int i = 0; i < 32; ++i)
        areg[i] = A[(igrp*32 + i)*DSt + s] * 1.44269504f;

    const float* delta = ws + OFF_DELTA;
    float*       Abar  = ws + OFF_ABAR;

#pragma unroll
    for (int t = 0; t < SEGLEN; ++t) {
        const float* dv = delta + (t0 + t)*DI + igrp*32;
        float a0=0.f,a1=0.f,a2=0.f,a3=0.f;
#pragma unroll
        for (int q = 0; q < 8; ++q) {
            const float4 d4 = *(const float4*)(dv + 4*q);   // uniform bcast
            a0 += fast_exp2(d4.x * areg[4*q    ]);
            a1 += fast_exp2(d4.y * areg[4*q + 1]);
            a2 += fast_exp2(d4.z * areg[4*q + 2]);
            a3 += fast_exp2(d4.w * areg[4*q + 3]);
        }
        psum[igrp][t][lane] = (a0+a1) + (a2+a3);
    }
    __syncthreads();

#pragma unroll
    for (int it = tid; it < SEGLEN*64; it += 256) {
        const int t = it >> 6, l2 = it & 63;
        float v = (psum[0][t][l2] + psum[1][t][l2])
                + (psum[2][t][l2] + psum[3][t][l2]);
        v *= (1.0f/DI);
        abL[t][l2] = v;
        Abar[(t0 + t)*DSt + sh*64 + l2] = v;
    }
    __syncthreads();

    if (tid < 64) {
        const float* Bm    = ws + OFF_BM;
        const float* xpool = ws + OFF_XPOOL;
        float bx[SEGLEN];
#pragma unroll
        for (int t = 0; t < SEGLEN; ++t)
            bx[t] = Bm[(t0 + t)*DSt + s] * xpool[t0 + t];
        float h = 0.f, pr = 1.f;
#pragma unroll
        for (int t = 0; t < SEGLEN; ++t) {
            const float a = abL[t][lane];
            h = fmaf(a, h, bx[t]);
            pr *= a;
        }
        ws[OFF_HEND + g*DSt + s] = h;
        ws[OFF_P    + g*DSt + s] = pr;
    }
}

// ---- K3: fused y + output, v3. grid = 512 blocks x 256 threads.
// Phase B rework: each wave holds ITS QUARTER of W4 in 8 f4 regs (loaded in
// pre-phase, lands under phase A) and partials ALL 8 tokens -> psum LDS ->
// cross-wave reduce + residual + LN. W4 L2 traffic: 128 MB -> 16 MB. ----
__global__ __launch_bounds__(256) void k_tail(
    const float* __restrict__ x, const float* __restrict__ ln_w,
    const float* __restrict__ ln_b, const float* __restrict__ ws,
    float* __restrict__ out)
{
    __shared__ float prod[SEGLEN][132];     // 4.2 KB
    __shared__ float y_lds[SEGLEN];
    __shared__ float vall[SEGLEN][DI];      // 4 KB
    __shared__ float psum[4][SEGLEN][64];   // 8 KB

    const int tid = threadIdx.x;
    const int b   = blockIdx.x >> 7;
    const int seg = blockIdx.x & 127;
    const int t0  = b*SL + seg*SEGLEN;
    const int d   = tid & 63;
    const int wv  = tid >> 6;

    // pre-phase: issue ALL phase-B operand loads (land under phase A)
    const float* gate = ws + OFF_GATE;
    const float4* W4  = (const float4*)(ws + OFF_W4);
    float gv[4];
#pragma unroll
    for (int j = 0; j < 4; ++j) {
        const int idx = j*256 + tid;            // (tl, dd)
        const int tl = idx >> 7, dd = idx & 127;
        gv[j] = gate[(t0 + tl)*DI + dd];        // coalesced
    }
    float4 wq[8];
#pragma unroll
    for (int j = 0; j < 8; ++j)
        wq[j] = W4[(wv*8 + j)*64 + d];          // coalesced 1KB, L2-hot
    float xres[2];
#pragma unroll
    for (int jt = 0; jt < 2; ++jt)
        xres[jt] = x[(t0 + wv*2 + jt)*DM + d];
    const float lw = ln_w[d], lb = ln_b[d];

    // phase A (tid<128): stitch + rescan
    if (tid < 128) {
        const int s = tid;
        const float* Abar  = ws + OFF_ABAR;
        const float* Bm    = ws + OFF_BM;
        const float* Cm    = ws + OFF_CM;
        const float* xpool = ws + OFF_XPOOL;
        const float* hend  = ws + OFF_HEND;
        const float* P     = ws + OFF_P;

        float aA[SEGLEN], aB[SEGLEN], aC[SEGLEN];
#pragma unroll
        for (int t = 0; t < SEGLEN; ++t) {
            aA[t] = Abar[(t0 + t)*DSt + s];
            aB[t] = Bm[(t0 + t)*DSt + s] * xpool[t0 + t];
            aC[t] = Cm[(t0 + t)*DSt + s];
        }
        float h = 0.f;
#pragma unroll 8
        for (int j = 0; j < seg; ++j) {   // block-uniform trip count
            const int idx = (b*NSEG + j)*DSt + s;
            h = fmaf(P[idx], h, hend[idx]);
        }
#pragma unroll
        for (int t = 0; t < SEGLEN; ++t) {
            h = fmaf(aA[t], h, aB[t]);
            prod[t][s] = aC[t] * h;
        }
    }
    __syncthreads();

    if (tid < 128) {   // y reduce: 16 lanes per token
        const int t = tid >> 4, r = tid & 15;
        float4 u0 = *(const float4*)(&prod[t][r*8]);
        float4 u1 = *(const float4*)(&prod[t][r*8 + 4]);
        float acc = ((u0.x+u0.y) + (u0.z+u0.w)) + ((u1.x+u1.y) + (u1.z+u1.w));
#pragma unroll
        for (int m = 1; m <= 8; m <<= 1) acc += __shfl_xor(acc, m, 64);
        if (r == 0) y_lds[t] = acc;
    }
    __syncthreads();

    // B-1: v = y * silu(gate) for all 8 tokens -> vall (coalesced writes)
#pragma unroll
    for (int j = 0; j < 4; ++j) {
        const int idx = j*256 + tid;
        const int tl = idx >> 7, dd = idx & 127;
        const float g = gv[j];
        vall[tl][dd] = y_lds[tl] * (g / (1.f + __expf(-g)));
    }
    __syncthreads();

    // B-2: per-wave quarter matvec; W4 already in regs, v via LDS broadcast
    float ac[8];
#pragma unroll
    for (int t = 0; t < 8; ++t) ac[t] = 0.f;
#pragma unroll
    for (int j = 0; j < 8; ++j) {
        const float4 w4 = wq[j];
#pragma unroll
        for (int t = 0; t < 8; ++t) {
            const float4 v = *(const float4*)(&vall[t][(wv*8 + j)*4]); // bcast
            ac[t] = fmaf(w4.x, v.x, ac[t]);
            ac[t] = fmaf(w4.y, v.y, ac[t]);
            ac[t] = fmaf(w4.z, v.z, ac[t]);
            ac[t] = fmaf(w4.w, v.w, ac[t]);
        }
    }
#pragma unroll
    for (int t = 0; t < 8; ++t) psum[wv][t][d] = ac[t];   // conflict-free
    __syncthreads();

    // B-3: cross-wave reduce + residual + LN; wave wv -> tokens 2wv, 2wv+1
#pragma unroll
    for (int jt = 0; jt < 2; ++jt) {
        const int tl  = wv*2 + jt;
        const int tok = t0 + tl;
        const float z = ((psum[0][tl][d] + psum[1][tl][d])
                       + (psum[2][tl][d] + psum[3][tl][d])) + xres[jt];
        const float s1 = wave64_sum(z);
        const float s2 = wave64_sum(z*z);
        const float mu  = s1 * (1.f/64.f);
        const float var = s2 * (1.f/64.f) - mu*mu;
        out[tok*DM + d] = (z - mu) * rsqrtf(var + 1e-5f) * lw + lb;
    }
}

extern "C" void kernel_launch(void* const* d_in, const int* in_sizes, int n_in,
                              void* d_out, int out_size, void* d_ws, size_t ws_size,
                              hipStream_t stream) {
    const float* x       = (const float*)d_in[0];
    const float* W_in    = (const float*)d_in[1];
    const float* W_delta = (const float*)d_in[2];
    const float* b_delta = (const float*)d_in[3];
    const float* W_B     = (const float*)d_in[4];
    const float* b_B     = (const float*)d_in[5];
    const float* W_C     = (const float*)d_in[6];
    const float* b_C     = (const float*)d_in[7];
    const float* A       = (const float*)d_in[8];
    const float* W_out   = (const float*)d_in[9];
    const float* ln_w    = (const float*)d_in[10];
    const float* ln_b    = (const float*)d_in[11];
    float* out = (float*)d_out;
    float* ws  = (float*)d_ws;

    hipLaunchKernelGGL(k_proj, dim3(4*PROJ_TG + 1), dim3(256), 0, stream,
                       x, W_in, W_delta, b_delta, W_B, b_B, W_C, b_C, W_out, ws);
    hipLaunchKernelGGL(k_abar_scan1, dim3(2*NSEG_ALL), dim3(256), 0, stream, A, ws);
    hipLaunchKernelGGL(k_tail,       dim3(NSEG_ALL),   dim3(256), 0, stream,
                       x, ln_w, ln_b, ws, out);
}